// Round 1
// baseline (4201.394 us; speedup 1.0000x reference)
//
#include <hip/hip_runtime.h>
#include <hip/hip_bf16.h>
#include <math.h>

#define TTOK 2048
#define NEXP 16
#define HDIM 2048
#define IDIM 1408
#define TOPK 4

#define BM 64
#define BN 64
#define BK 32

__global__ void zero_f32(float* __restrict__ p, int n) {
    int i = blockIdx.x * blockDim.x + threadIdx.x;
    int stride = gridDim.x * blockDim.x;
    for (; i < n; i += stride) p[i] = 0.f;
}

__global__ void zero_i32(int* __restrict__ p, int n) {
    int i = threadIdx.x;
    if (i < n) p[i] = 0;
}

// One thread per token: top-4 of 16 logits, renormalized softmax over top-4,
// scatter (token, weight) into per-expert lists.
__global__ void router_kernel(const float* __restrict__ logits,
                              int* __restrict__ cnt,
                              int* __restrict__ tok_id,
                              float* __restrict__ tok_w) {
    int t = blockIdx.x * blockDim.x + threadIdx.x;
    if (t >= TTOK) return;
    float l[NEXP];
#pragma unroll
    for (int e = 0; e < NEXP; ++e) l[e] = logits[t * NEXP + e];

    int bi[TOPK]; float bv[TOPK];
    unsigned used = 0;
#pragma unroll
    for (int k = 0; k < TOPK; ++k) {
        float best = -1e30f; int b = 0;
#pragma unroll
        for (int e = 0; e < NEXP; ++e) {
            // strict > keeps lowest index on ties, matching jax.lax.top_k
            if (!((used >> e) & 1u) && l[e] > best) { best = l[e]; b = e; }
        }
        used |= 1u << b; bi[k] = b; bv[k] = best;
    }
    // softmax over all E then renormalize over top-k == softmax over top-k logits
    float m = bv[0];
    float w[TOPK]; float s = 0.f;
#pragma unroll
    for (int k = 0; k < TOPK; ++k) { w[k] = expf(bv[k] - m); s += w[k]; }
    float inv = 1.f / s;
#pragma unroll
    for (int k = 0; k < TOPK; ++k) {
        int e = bi[k];
        int pos = atomicAdd(&cnt[e], 1);
        tok_id[e * TTOK + pos] = t;
        tok_w[e * TTOK + pos] = w[k] * inv;
    }
}

__global__ void scan_kernel(const int* __restrict__ cnt, int* __restrict__ offs) {
    if (threadIdx.x == 0 && blockIdx.x == 0) {
        int a = 0;
        for (int e = 0; e < NEXP; ++e) { offs[e] = a; a += cnt[e]; }
        offs[NEXP] = a;
    }
}

// Grouped gate/up GEMM for one expert tile: G = X_e * gate_w[e]^T, U likewise,
// h = combine_w * silu(G) * U  -> hbuf (compact rows, [sum_counts, IDIM]).
__launch_bounds__(256)
__global__ void gateup_kernel(const float* __restrict__ x,
                              const float* __restrict__ gate_w,
                              const float* __restrict__ up_w,
                              const int* __restrict__ cnt,
                              const int* __restrict__ offs,
                              const int* __restrict__ tok_id,
                              const float* __restrict__ tok_w,
                              float* __restrict__ hbuf) {
    const int e  = blockIdx.z;
    const int n  = cnt[e];
    const int m0 = blockIdx.y * BM;
    if (m0 >= n) return;
    const int i0 = blockIdx.x * BN;

    __shared__ float As[BM][BK + 1];
    __shared__ float Bg[BN][BK + 1];
    __shared__ float Bu[BN][BK + 1];

    const int tid = threadIdx.x;
    const int ty = tid >> 4;
    const int tx = tid & 15;

    const float* gw = gate_w + (size_t)e * IDIM * HDIM;
    const float* uw = up_w   + (size_t)e * IDIM * HDIM;

    float ag[4][4] = {};
    float au[4][4] = {};

    for (int k0 = 0; k0 < HDIM; k0 += BK) {
        __syncthreads();
        for (int l = tid; l < BM * BK; l += 256) {
            int mm = l >> 5, kk = l & 31;
            int slot = m0 + mm;
            float v = 0.f;
            if (slot < n) {
                int t = tok_id[e * TTOK + slot];
                v = x[t * HDIM + k0 + kk];
            }
            As[mm][kk] = v;
            Bg[mm][kk] = gw[(size_t)(i0 + mm) * HDIM + k0 + kk];
            Bu[mm][kk] = uw[(size_t)(i0 + mm) * HDIM + k0 + kk];
        }
        __syncthreads();
#pragma unroll
        for (int kk = 0; kk < BK; ++kk) {
            float a[4], bg[4], bu[4];
#pragma unroll
            for (int i = 0; i < 4; ++i) a[i] = As[ty * 4 + i][kk];
#pragma unroll
            for (int j = 0; j < 4; ++j) { bg[j] = Bg[tx * 4 + j][kk]; bu[j] = Bu[tx * 4 + j][kk]; }
#pragma unroll
            for (int i = 0; i < 4; ++i)
#pragma unroll
                for (int j = 0; j < 4; ++j) {
                    ag[i][j] += a[i] * bg[j];
                    au[i][j] += a[i] * bu[j];
                }
        }
    }

    const int rbase = offs[e];
#pragma unroll
    for (int i = 0; i < 4; ++i) {
        int slot = m0 + ty * 4 + i;
        if (slot >= n) continue;
        float wgt = tok_w[e * TTOK + slot];
        size_t r = (size_t)(rbase + slot) * IDIM;
#pragma unroll
        for (int j = 0; j < 4; ++j) {
            float g = ag[i][j], u = au[i][j];
            float h = (g / (1.f + expf(-g))) * u * wgt;
            hbuf[r + i0 + tx * 4 + j] = h;
        }
    }
}

// Grouped down GEMM: out[t,:] += hbuf_row * down_w[e]^T (h already carries combine weight)
__launch_bounds__(256)
__global__ void down_kernel(const float* __restrict__ hbuf,
                            const float* __restrict__ down_w,
                            const int* __restrict__ cnt,
                            const int* __restrict__ offs,
                            const int* __restrict__ tok_id,
                            float* __restrict__ out) {
    const int e  = blockIdx.z;
    const int n  = cnt[e];
    const int m0 = blockIdx.y * BM;
    if (m0 >= n) return;
    const int h0 = blockIdx.x * BN;

    __shared__ float As[BM][BK + 1];
    __shared__ float Bs[BN][BK + 1];

    const int tid = threadIdx.x;
    const int ty = tid >> 4;
    const int tx = tid & 15;

    const float* dw = down_w + (size_t)e * HDIM * IDIM;
    const int rbase = offs[e];

    float acc[4][4] = {};

    for (int k0 = 0; k0 < IDIM; k0 += BK) {
        __syncthreads();
        for (int l = tid; l < BM * BK; l += 256) {
            int mm = l >> 5, kk = l & 31;
            int slot = m0 + mm;
            float v = 0.f;
            if (slot < n) v = hbuf[(size_t)(rbase + slot) * IDIM + k0 + kk];
            As[mm][kk] = v;
            Bs[mm][kk] = dw[(size_t)(h0 + mm) * IDIM + k0 + kk];
        }
        __syncthreads();
#pragma unroll
        for (int kk = 0; kk < BK; ++kk) {
            float a[4], b[4];
#pragma unroll
            for (int i = 0; i < 4; ++i) a[i] = As[ty * 4 + i][kk];
#pragma unroll
            for (int j = 0; j < 4; ++j) b[j] = Bs[tx * 4 + j][kk];
#pragma unroll
            for (int i = 0; i < 4; ++i)
#pragma unroll
                for (int j = 0; j < 4; ++j) acc[i][j] += a[i] * b[j];
        }
    }

#pragma unroll
    for (int i = 0; i < 4; ++i) {
        int slot = m0 + ty * 4 + i;
        if (slot >= n) continue;
        int t = tok_id[e * TTOK + slot];
#pragma unroll
        for (int j = 0; j < 4; ++j) {
            atomicAdd(&out[t * HDIM + h0 + tx * 4 + j], acc[i][j]);
        }
    }
}

extern "C" void kernel_launch(void* const* d_in, const int* in_sizes, int n_in,
                              void* d_out, int out_size, void* d_ws, size_t ws_size,
                              hipStream_t stream) {
    const float* x      = (const float*)d_in[0];
    const float* logits = (const float*)d_in[1];
    const float* gate_w = (const float*)d_in[2];
    const float* up_w   = (const float*)d_in[3];
    const float* down_w = (const float*)d_in[4];
    float* out = (float*)d_out;

    char* ws = (char*)d_ws;
    int*   cnt    = (int*)(ws);                               // 16 ints
    int*   offs   = (int*)(ws + 64);                          // 17 ints
    int*   tok_id = (int*)(ws + 256);                         // 16*2048 ints
    float* tok_w  = (float*)(ws + 256 + TTOK * NEXP * 4);     // 16*2048 floats
    float* hbuf   = (float*)(ws + 256 + 2 * TTOK * NEXP * 4); // 8192*1408 floats (~44 MB)

    zero_i32<<<1, 32, 0, stream>>>(cnt, NEXP);
    zero_f32<<<1024, 256, 0, stream>>>(out, TTOK * HDIM);
    router_kernel<<<TTOK / 256, 256, 0, stream>>>(logits, cnt, tok_id, tok_w);
    scan_kernel<<<1, 1, 0, stream>>>(cnt, offs);

    dim3 g1(IDIM / BN, TTOK / BM, NEXP);
    gateup_kernel<<<g1, 256, 0, stream>>>(x, gate_w, up_w, cnt, offs, tok_id, tok_w, hbuf);

    dim3 g2(HDIM / BN, TTOK / BM, NEXP);
    down_kernel<<<g2, 256, 0, stream>>>(hbuf, down_w, cnt, offs, tok_id, out);
}

// Round 2
// 1071.273 us; speedup vs baseline: 3.9219x; 3.9219x over previous
//
#include <hip/hip_runtime.h>
#include <hip/hip_bf16.h>
#include <math.h>

#define TTOK 2048
#define NEXP 16
#define HDIM 2048
#define IDIM 1408
#define TOPK 4

typedef __attribute__((ext_vector_type(8))) short short8;
typedef __attribute__((ext_vector_type(4))) float floatx4;

#define GUP ((size_t)NEXP * IDIM * HDIM)  // elems in gate_w / up_w / down_w (46.1M each)

#define LDSP(p) ((__attribute__((address_space(3))) void*)(p))
#define GLBP(p) ((const __attribute__((address_space(1))) void*)(p))

__device__ __forceinline__ unsigned short f2bf(float f) {
    unsigned u = __builtin_bit_cast(unsigned, f);
    u += 0x7FFFu + ((u >> 16) & 1u);   // round-to-nearest-even
    return (unsigned short)(u >> 16);
}

__device__ __forceinline__ void cvt8(const float* __restrict__ s, unsigned short* __restrict__ d) {
    const float4* sv = (const float4*)s;
    float4 a = sv[0], b = sv[1];
    union { unsigned short h[8]; uint4 v; } p;
    p.h[0] = f2bf(a.x); p.h[1] = f2bf(a.y); p.h[2] = f2bf(a.z); p.h[3] = f2bf(a.w);
    p.h[4] = f2bf(b.x); p.h[5] = f2bf(b.y); p.h[6] = f2bf(b.z); p.h[7] = f2bf(b.w);
    *(uint4*)d = p.v;
}

__global__ void zero_f32(float* __restrict__ p, size_t n) {
    size_t i = (size_t)blockIdx.x * blockDim.x + threadIdx.x;
    size_t stride = (size_t)gridDim.x * blockDim.x;
    for (; i < n; i += stride) p[i] = 0.f;
}

__global__ void zero_i32(int* __restrict__ p, int n) {
    int i = threadIdx.x;
    if (i < n) p[i] = 0;
}

// fp32 -> bf16 cast of the three weight tensors (8 elems/thread/array per iter)
__global__ void cast_weights(const float* __restrict__ g, const float* __restrict__ u,
                             const float* __restrict__ d,
                             unsigned short* __restrict__ og, unsigned short* __restrict__ ou,
                             unsigned short* __restrict__ od) {
    size_t i = ((size_t)blockIdx.x * blockDim.x + threadIdx.x) * 8;
    size_t stride = (size_t)gridDim.x * blockDim.x * 8;
    for (; i < GUP; i += stride) {
        cvt8(g + i, og + i);
        cvt8(u + i, ou + i);
        cvt8(d + i, od + i);
    }
}

// One thread per token: top-4 of 16 logits, softmax over the top-4 (== softmax
// over all then renormalize), scatter (token, weight) into per-expert lists.
__global__ void router_kernel(const float* __restrict__ logits,
                              int* __restrict__ cnt,
                              int* __restrict__ tok_id,
                              float* __restrict__ tok_w) {
    int t = blockIdx.x * blockDim.x + threadIdx.x;
    if (t >= TTOK) return;
    float l[NEXP];
#pragma unroll
    for (int e = 0; e < NEXP; ++e) l[e] = logits[t * NEXP + e];
    int bi[TOPK]; float bv[TOPK];
    unsigned used = 0;
#pragma unroll
    for (int k = 0; k < TOPK; ++k) {
        float best = -1e30f; int b = 0;
#pragma unroll
        for (int e = 0; e < NEXP; ++e) {
            if (!((used >> e) & 1u) && l[e] > best) { best = l[e]; b = e; }
        }
        used |= 1u << b; bi[k] = b; bv[k] = best;
    }
    float m = bv[0], w[TOPK], s = 0.f;
#pragma unroll
    for (int k = 0; k < TOPK; ++k) { w[k] = expf(bv[k] - m); s += w[k]; }
    float inv = 1.f / s;
#pragma unroll
    for (int k = 0; k < TOPK; ++k) {
        int e = bi[k];
        int pos = atomicAdd(&cnt[e], 1);
        tok_id[e * TTOK + pos] = t;
        tok_w[e * TTOK + pos] = w[k] * inv;
    }
}

// Cumulative offsets with each expert padded to a multiple of 128 rows.
__global__ void scan_kernel(const int* __restrict__ cnt, int* __restrict__ offs) {
    if (threadIdx.x == 0 && blockIdx.x == 0) {
        int a = 0;
        for (int e = 0; e < NEXP; ++e) {
            offs[e] = a;
            a += (cnt[e] + 127) & ~127;
        }
        offs[NEXP] = a;
    }
}

// Gather + cast x rows into compact padded per-expert layout (pad rows zeroed).
__global__ void gather_x(const float* __restrict__ x, const int* __restrict__ cnt,
                         const int* __restrict__ offs, const int* __restrict__ tok_id,
                         unsigned short* __restrict__ xg) {
    int e = blockIdx.y, slot = blockIdx.x;
    int n = cnt[e];
    int padcap = (n + 127) & ~127;
    if (slot >= padcap) return;
    unsigned short* dst = xg + (size_t)(offs[e] + slot) * HDIM;
    int tid = threadIdx.x;  // 256 threads, 8 elems each = 2048
    if (slot < n) {
        const float* src = x + (size_t)tok_id[e * TTOK + slot] * HDIM;
        cvt8(src + tid * 8, dst + tid * 8);
    } else {
        uint4 z = {0u, 0u, 0u, 0u};
        ((uint4*)dst)[tid] = z;
    }
}

// Fused gate+up MFMA GEMM: 128x128 tile, BK=64, 4 waves (2x2), 4x4 16x16x32
// fragments per wave, two accumulators; epilogue h = silu(g)*u*combine -> bf16.
__launch_bounds__(256)
__global__ void gateup_mfma(const unsigned short* __restrict__ xg,
                            const unsigned short* __restrict__ gw,
                            const unsigned short* __restrict__ uw,
                            const int* __restrict__ cnt, const int* __restrict__ offs,
                            const float* __restrict__ tok_w,
                            unsigned short* __restrict__ hbuf) {
    const int e = blockIdx.z;
    const int n = cnt[e];
    const int m0 = blockIdx.y * 128;
    if (m0 >= n) return;
    const int i0 = blockIdx.x * 128;
    const int rowbase = offs[e];

    __shared__ __align__(16) unsigned short sA[128 * 64];
    __shared__ __align__(16) unsigned short sBg[128 * 64];
    __shared__ __align__(16) unsigned short sBu[128 * 64];

    const int tid = threadIdx.x;
    const int lane = tid & 63;
    const int wave = tid >> 6;
    const int wm = wave >> 1;
    const int wn = wave & 1;

    const unsigned short* Abase = xg + (size_t)(rowbase + m0) * HDIM;
    const unsigned short* Gbase = gw + (size_t)e * IDIM * HDIM + (size_t)i0 * HDIM;
    const unsigned short* Ubase = uw + (size_t)e * IDIM * HDIM + (size_t)i0 * HDIM;

    floatx4 accg[4][4], accu[4][4];
#pragma unroll
    for (int i = 0; i < 4; ++i)
#pragma unroll
        for (int j = 0; j < 4; ++j) {
            accg[i][j] = (floatx4){0.f, 0.f, 0.f, 0.f};
            accu[i][j] = (floatx4){0.f, 0.f, 0.f, 0.f};
        }

    const int lrow = lane >> 3;       // row within 8-row chunk
    const int lcol = (lane & 7) * 8;  // elem col within 64-wide K slab

    for (int k0 = 0; k0 < HDIM; k0 += 64) {
        for (int c = wave; c < 48; c += 4) {
            int t = c >> 4;    // 0=A, 1=Bg, 2=Bu
            int ch = c & 15;
            int r = ch * 8 + lrow;
            const unsigned short* gsrc =
                (t == 0) ? Abase + (size_t)r * HDIM + k0 + lcol
              : (t == 1) ? Gbase + (size_t)r * HDIM + k0 + lcol
                         : Ubase + (size_t)r * HDIM + k0 + lcol;
            unsigned short* lds = ((t == 0) ? sA : (t == 1) ? sBg : sBu) + ch * 512 + lane * 8;
            __builtin_amdgcn_global_load_lds(GLBP(gsrc), LDSP(lds), 16, 0, 0);
        }
        __syncthreads();
#pragma unroll
        for (int s = 0; s < 2; ++s) {
            short8 af[4], bg[4], bu[4];
            const int ko = s * 32 + (lane >> 4) * 8;
            const int mrow = wm * 64 + (lane & 15);
            const int nrow = wn * 64 + (lane & 15);
#pragma unroll
            for (int i = 0; i < 4; ++i)
                af[i] = *(const short8*)&sA[(mrow + i * 16) * 64 + ko];
#pragma unroll
            for (int j = 0; j < 4; ++j) {
                bg[j] = *(const short8*)&sBg[(nrow + j * 16) * 64 + ko];
                bu[j] = *(const short8*)&sBu[(nrow + j * 16) * 64 + ko];
            }
#pragma unroll
            for (int i = 0; i < 4; ++i)
#pragma unroll
                for (int j = 0; j < 4; ++j) {
                    accg[i][j] = __builtin_amdgcn_mfma_f32_16x16x32_bf16(af[i], bg[j], accg[i][j], 0, 0, 0);
                    accu[i][j] = __builtin_amdgcn_mfma_f32_16x16x32_bf16(af[i], bu[j], accu[i][j], 0, 0, 0);
                }
        }
        __syncthreads();
    }

    const int q = lane >> 4;
    const int cl = lane & 15;
#pragma unroll
    for (int i = 0; i < 4; ++i) {
#pragma unroll
        for (int r = 0; r < 4; ++r) {
            int slot = m0 + wm * 64 + i * 16 + q * 4 + r;
            if (slot < n) {
                float wgt = tok_w[e * TTOK + slot];
                size_t rowoff = (size_t)(rowbase + slot) * IDIM + i0 + wn * 64 + cl;
#pragma unroll
                for (int j = 0; j < 4; ++j) {
                    float g = accg[i][j][r];
                    float u = accu[i][j][r];
                    float h = (g / (1.f + __expf(-g))) * u * wgt;
                    hbuf[rowoff + j * 16] = f2bf(h);
                }
            }
        }
    }
}

// Down-proj MFMA GEMM, atomicAdd into zeroed out (combine weight already in h).
__launch_bounds__(256)
__global__ void down_mfma(const unsigned short* __restrict__ hbuf,
                          const unsigned short* __restrict__ dw,
                          const int* __restrict__ cnt, const int* __restrict__ offs,
                          const int* __restrict__ tok_id,
                          float* __restrict__ out) {
    const int e = blockIdx.z;
    const int n = cnt[e];
    const int m0 = blockIdx.y * 128;
    if (m0 >= n) return;
    const int h0 = blockIdx.x * 128;
    const int rowbase = offs[e];

    __shared__ __align__(16) unsigned short sA[128 * 64];
    __shared__ __align__(16) unsigned short sB[128 * 64];

    const int tid = threadIdx.x;
    const int lane = tid & 63;
    const int wave = tid >> 6;
    const int wm = wave >> 1;
    const int wn = wave & 1;

    const unsigned short* Abase = hbuf + (size_t)(rowbase + m0) * IDIM;
    const unsigned short* Bbase = dw + (size_t)e * HDIM * IDIM + (size_t)h0 * IDIM;

    floatx4 acc[4][4];
#pragma unroll
    for (int i = 0; i < 4; ++i)
#pragma unroll
        for (int j = 0; j < 4; ++j) acc[i][j] = (floatx4){0.f, 0.f, 0.f, 0.f};

    const int lrow = lane >> 3;
    const int lcol = (lane & 7) * 8;

    for (int k0 = 0; k0 < IDIM; k0 += 64) {
        for (int c = wave; c < 32; c += 4) {
            int t = c >> 4;   // 0=A, 1=B
            int ch = c & 15;
            int r = ch * 8 + lrow;
            const unsigned short* gsrc =
                (t == 0) ? Abase + (size_t)r * IDIM + k0 + lcol
                         : Bbase + (size_t)r * IDIM + k0 + lcol;
            unsigned short* lds = ((t == 0) ? sA : sB) + ch * 512 + lane * 8;
            __builtin_amdgcn_global_load_lds(GLBP(gsrc), LDSP(lds), 16, 0, 0);
        }
        __syncthreads();
#pragma unroll
        for (int s = 0; s < 2; ++s) {
            short8 af[4], bf[4];
            const int ko = s * 32 + (lane >> 4) * 8;
            const int mrow = wm * 64 + (lane & 15);
            const int nrow = wn * 64 + (lane & 15);
#pragma unroll
            for (int i = 0; i < 4; ++i)
                af[i] = *(const short8*)&sA[(mrow + i * 16) * 64 + ko];
#pragma unroll
            for (int j = 0; j < 4; ++j)
                bf[j] = *(const short8*)&sB[(nrow + j * 16) * 64 + ko];
#pragma unroll
            for (int i = 0; i < 4; ++i)
#pragma unroll
                for (int j = 0; j < 4; ++j)
                    acc[i][j] = __builtin_amdgcn_mfma_f32_16x16x32_bf16(af[i], bf[j], acc[i][j], 0, 0, 0);
        }
        __syncthreads();
    }

    const int q = lane >> 4;
    const int cl = lane & 15;
#pragma unroll
    for (int i = 0; i < 4; ++i) {
#pragma unroll
        for (int r = 0; r < 4; ++r) {
            int slot = m0 + wm * 64 + i * 16 + q * 4 + r;
            if (slot < n) {
                int t = tok_id[e * TTOK + slot];
                float* orow = out + (size_t)t * HDIM + h0 + wn * 64 + cl;
#pragma unroll
                for (int j = 0; j < 4; ++j) atomicAdd(&orow[j * 16], acc[i][j][r]);
            }
        }
    }
}

extern "C" void kernel_launch(void* const* d_in, const int* in_sizes, int n_in,
                              void* d_out, int out_size, void* d_ws, size_t ws_size,
                              hipStream_t stream) {
    const float* x      = (const float*)d_in[0];
    const float* logits = (const float*)d_in[1];
    const float* gate_w = (const float*)d_in[2];
    const float* up_w   = (const float*)d_in[3];
    const float* down_w = (const float*)d_in[4];
    float* out = (float*)d_out;

    char* ws = (char*)d_ws;
    // metadata
    int*   cnt    = (int*)(ws);
    int*   offs   = (int*)(ws + 64);
    int*   tok_id = (int*)(ws + 1024);
    float* tok_w  = (float*)(ws + 1024 + TTOK * NEXP * 4);
    // bf16 weights at 1 MB
    unsigned short* gate_bf = (unsigned short*)(ws + (1u << 20));
    unsigned short* up_bf   = gate_bf + GUP;
    unsigned short* down_bf = up_bf + GUP;
    // gathered x (10240 x 2048 bf16) at 280 MB
    unsigned short* xg   = (unsigned short*)(ws + (size_t)280 * (1u << 20));
    // h buffer (10240 x 1408 bf16) at 321 MB
    unsigned short* hbuf = (unsigned short*)(ws + (size_t)321 * (1u << 20));

    zero_i32<<<1, 32, 0, stream>>>(cnt, NEXP);
    zero_f32<<<1024, 256, 0, stream>>>(out, (size_t)TTOK * HDIM);
    cast_weights<<<4096, 256, 0, stream>>>(gate_w, up_w, down_w, gate_bf, up_bf, down_bf);
    router_kernel<<<TTOK / 256, 256, 0, stream>>>(logits, cnt, tok_id, tok_w);
    scan_kernel<<<1, 1, 0, stream>>>(cnt, offs);
    {
        dim3 g(TTOK, NEXP);
        gather_x<<<g, 256, 0, stream>>>(x, cnt, offs, tok_id, xg);
    }
    {
        dim3 g(IDIM / 128, TTOK / 128, NEXP);
        gateup_mfma<<<g, 256, 0, stream>>>(xg, gate_bf, up_bf, cnt, offs, tok_w, hbuf);
    }
    {
        dim3 g(HDIM / 128, TTOK / 128, NEXP);
        down_mfma<<<g, 256, 0, stream>>>(hbuf, down_bf, cnt, offs, tok_id, out);
    }
}